// Round 6
// baseline (364.936 us; speedup 1.0000x reference)
//
#include <hip/hip_runtime.h>
#include <hip/hip_cooperative_groups.h>
#include <cstdint>
#include <cstddef>

namespace cg = cooperative_groups;

typedef unsigned short ushort_t;
typedef __attribute__((ext_vector_type(8))) short short8;
typedef __attribute__((ext_vector_type(4))) float float4_;

#define GLOBAL_AS __attribute__((address_space(1)))
#define LDS_AS    __attribute__((address_space(3)))

#define D_FEAT 512
#define KDIM   1024
#define CAP    80     // bucket capacity; deg ~ Poisson(16), P(>80) ~ 1e-30

__device__ __forceinline__ ushort_t f2bf(float f) {
    union { float f; unsigned int i; } v; v.f = f;
    unsigned int x = v.i;
    unsigned int r = (x + 0x7fffu + ((x >> 16) & 1u)) >> 16;
    return (ushort_t)r;
}
__device__ __forceinline__ float bfbits_lo(unsigned int u) {
    union { unsigned int i; float f; } v; v.i = u << 16; return v.f;
}
__device__ __forceinline__ float bfbits_hi(unsigned int u) {
    union { unsigned int i; float f; } v; v.i = u & 0xffff0000u; return v.f;
}

// ---------------------------------------------------------------------------
// One cooperative mega-kernel; phases separated by grid.sync():
//  A: transpose W->BT bf16 | zero cnt | copy x->bf16 xb      (independent)
//  B: bucket scatter of edges (atomic bump per dst)
//  C: per-node gather-mean (bf16, fp32 accum) -> mb
//  D: GEMM out = swish([mb|xb] . BT^T + bias), 128x64 tiles grid-stride
// ---------------------------------------------------------------------------
__global__ __launch_bounds__(256) void mega_kernel(
    const float* __restrict__ Wl, const float* __restrict__ Wr,
    const float* __restrict__ x, const int* __restrict__ ei,
    const float* __restrict__ bias, ushort_t* __restrict__ BT,
    ushort_t* __restrict__ xb, ushort_t* __restrict__ mb,
    int* __restrict__ cnt, int* __restrict__ colbuf,
    float* __restrict__ out, int N, int E, int M_PAD, int G) {
    __shared__ ushort_t smem[6144];   // 12 KB: gemm As(4096)+Bs(2048); transpose tile 64x72
    cg::grid_group grid = cg::this_grid();
    int b = blockIdx.x;
    int t = threadIdx.x;

    // ---- Phase A ----
    if (b < 128) {
        // transpose [Wl;Wr] fp32 -> bf16 BT[n][k]
        ushort_t (*tile)[72] = (ushort_t (*)[72])smem;
        int kb = (b & 15) * 64, nb = (b >> 4) * 64;
#pragma unroll
        for (int ph = 0; ph < 4; ++ph) {
            int f = t * 4 + ph * 1024;
            int k = f >> 6, n = f & 63;
            int gk = kb + k;
            const float* W = (gk < 512) ? (Wl + (size_t)gk * 512 + nb + n)
                                        : (Wr + (size_t)(gk - 512) * 512 + nb + n);
            float4 v = *(const float4*)W;
            ushort_t o[4] = {f2bf(v.x), f2bf(v.y), f2bf(v.z), f2bf(v.w)};
            *(uint2*)&tile[k][n] = *(const uint2*)o;
        }
        __syncthreads();
#pragma unroll
        for (int ph = 0; ph < 4; ++ph) {
            int f = t * 4 + ph * 1024;
            int n = f >> 6, k = f & 63;
            ushort_t tmp[4];
#pragma unroll
            for (int j = 0; j < 4; ++j) tmp[j] = tile[k + j][n];
            *(uint2*)&BT[(size_t)(nb + n) * KDIM + kb + k] = *(const uint2*)tmp;
        }
    } else if (b < 168) {
        int zi = (b - 128) * 256 + t;
        if (zi < M_PAD) cnt[zi] = 0;
    } else {
        int nch = N * (D_FEAT / 4);
        int stride = (G - 168) * 256;
        for (int idx = (b - 168) * 256 + t; idx < nch; idx += stride) {
            int row = idx >> 7;
            int c = (idx & 127) << 2;
            float4 v = *(const float4*)&x[(size_t)row * D_FEAT + c];
            ushort_t o[4] = {f2bf(v.x), f2bf(v.y), f2bf(v.z), f2bf(v.w)};
            *(uint2*)&xb[(size_t)row * D_FEAT + c] = *(const uint2*)o;
        }
    }
    grid.sync();

    // ---- Phase B: bucket scatter ----
    for (int e = b * 256 + t; e < E; e += G * 256) {
        int d = ei[E + e];
        int p = atomicAdd(&cnt[d], 1);
        if (p < CAP) colbuf[(size_t)d * CAP + p] = ei[e];
    }
    grid.sync();

    // ---- Phase C: gather-mean ----
    {
        int w = t >> 6, l = t & 63;
        int f = l << 3;
        const ushort_t* gsrc = xb + f;
        for (int node = b * 4 + w; node < N; node += G * 4) {
            const int* bucket = colbuf + (size_t)node * CAP;
            float acc[8] = {0.f, 0.f, 0.f, 0.f, 0.f, 0.f, 0.f, 0.f};
            int deg = cnt[node];
            int e = deg < CAP ? deg : CAP;
            int j = 0;
            for (; j + 3 < e; j += 4) {
                int s0 = bucket[j], s1 = bucket[j + 1];
                int s2 = bucket[j + 2], s3 = bucket[j + 3];
                uint4 v0 = *(const uint4*)(gsrc + (size_t)s0 * D_FEAT);
                uint4 v1 = *(const uint4*)(gsrc + (size_t)s1 * D_FEAT);
                uint4 v2 = *(const uint4*)(gsrc + (size_t)s2 * D_FEAT);
                uint4 v3 = *(const uint4*)(gsrc + (size_t)s3 * D_FEAT);
                acc[0] += bfbits_lo(v0.x); acc[1] += bfbits_hi(v0.x);
                acc[2] += bfbits_lo(v0.y); acc[3] += bfbits_hi(v0.y);
                acc[4] += bfbits_lo(v0.z); acc[5] += bfbits_hi(v0.z);
                acc[6] += bfbits_lo(v0.w); acc[7] += bfbits_hi(v0.w);
                acc[0] += bfbits_lo(v1.x); acc[1] += bfbits_hi(v1.x);
                acc[2] += bfbits_lo(v1.y); acc[3] += bfbits_hi(v1.y);
                acc[4] += bfbits_lo(v1.z); acc[5] += bfbits_hi(v1.z);
                acc[6] += bfbits_lo(v1.w); acc[7] += bfbits_hi(v1.w);
                acc[0] += bfbits_lo(v2.x); acc[1] += bfbits_hi(v2.x);
                acc[2] += bfbits_lo(v2.y); acc[3] += bfbits_hi(v2.y);
                acc[4] += bfbits_lo(v2.z); acc[5] += bfbits_hi(v2.z);
                acc[6] += bfbits_lo(v2.w); acc[7] += bfbits_hi(v2.w);
                acc[0] += bfbits_lo(v3.x); acc[1] += bfbits_hi(v3.x);
                acc[2] += bfbits_lo(v3.y); acc[3] += bfbits_hi(v3.y);
                acc[4] += bfbits_lo(v3.z); acc[5] += bfbits_hi(v3.z);
                acc[6] += bfbits_lo(v3.w); acc[7] += bfbits_hi(v3.w);
            }
            for (; j < e; ++j) {
                int s0 = bucket[j];
                uint4 v0 = *(const uint4*)(gsrc + (size_t)s0 * D_FEAT);
                acc[0] += bfbits_lo(v0.x); acc[1] += bfbits_hi(v0.x);
                acc[2] += bfbits_lo(v0.y); acc[3] += bfbits_hi(v0.y);
                acc[4] += bfbits_lo(v0.z); acc[5] += bfbits_hi(v0.z);
                acc[6] += bfbits_lo(v0.w); acc[7] += bfbits_hi(v0.w);
            }
            float scale = 1.0f / (float)(deg > 1 ? deg : 1);
            ushort_t o[8];
#pragma unroll
            for (int k = 0; k < 8; ++k) o[k] = f2bf(acc[k] * scale);
            *(uint4*)&mb[(size_t)node * D_FEAT + f] = *(const uint4*)o;
        }
    }
    grid.sync();

    // ---- Phase D: GEMM 128x64 tiles, grid-stride ----
    {
        ushort_t* As = smem;           // 128*32
        ushort_t* Bs = smem + 4096;    // 64*32
        int w = t >> 6, l = t & 63;
        int lm = l & 15, q = l >> 4;
        int wm = w * 32;
        int c0 = w * 64 + l;
        int ntiles = (D_FEAT / 64) * (M_PAD / 128);   // 8 * MT

        for (int tile_i = b; tile_i < ntiles; tile_i += G) {
            int tile_n = (tile_i & 7) * 64;
            int tile_m = (tile_i >> 3) * 128;

            float4_ acc[2][4];
#pragma unroll
            for (int i = 0; i < 2; ++i)
#pragma unroll
                for (int j = 0; j < 4; ++j) acc[i][j] = (float4_)(0.f);

            for (int k0 = 0; k0 < KDIM; k0 += 32) {
                const ushort_t* Asrc = (k0 < 512) ? mb : xb;
                int kk = k0 & 511;
#pragma unroll
                for (int ph = 0; ph < 2; ++ph) {
                    int c = c0 + ph * 256;
                    int row = c >> 2;
                    int koff = (c & 3) << 3;
                    const ushort_t* gp =
                        Asrc + (size_t)(tile_m + row) * D_FEAT + kk + koff;
                    __builtin_amdgcn_global_load_lds(
                        (const GLOBAL_AS unsigned int*)gp,
                        (LDS_AS unsigned int*)&As[c * 8], 16, 0, 0);
                }
                {
                    int c = c0;
                    int row = c >> 2;
                    int koff = (c & 3) << 3;
                    const ushort_t* gq =
                        BT + (size_t)(tile_n + row) * KDIM + k0 + koff;
                    __builtin_amdgcn_global_load_lds(
                        (const GLOBAL_AS unsigned int*)gq,
                        (LDS_AS unsigned int*)&Bs[c * 8], 16, 0, 0);
                }
                __syncthreads();

                short8 a[2], bb[4];
#pragma unroll
                for (int i = 0; i < 2; ++i) {
                    int row = wm + i * 16 + lm;
                    a[i] = *(const short8*)&As[row * 32 + q * 8];
                }
#pragma unroll
                for (int j = 0; j < 4; ++j) {
                    int col = j * 16 + lm;
                    bb[j] = *(const short8*)&Bs[col * 32 + q * 8];
                }
#pragma unroll
                for (int i = 0; i < 2; ++i)
#pragma unroll
                    for (int j = 0; j < 4; ++j)
                        acc[i][j] = __builtin_amdgcn_mfma_f32_16x16x32_bf16(
                            a[i], bb[j], acc[i][j], 0, 0, 0);
                __syncthreads();
            }

#pragma unroll
            for (int j = 0; j < 4; ++j) {
                int gcol = tile_n + j * 16 + lm;
                float bv = bias[gcol];
#pragma unroll
                for (int i = 0; i < 2; ++i) {
#pragma unroll
                    for (int r = 0; r < 4; ++r) {
                        int grow = tile_m + wm + i * 16 + q * 4 + r;
                        if (grow < N) {
                            float h = acc[i][j][r] + bv;
                            float sw = h / (1.f + __expf(-h));
                            out[(size_t)grow * D_FEAT + gcol] = sw;
                        }
                    }
                }
            }
        }
    }
}

// ---------------------------------------------------------------------------
extern "C" void kernel_launch(void* const* d_in, const int* in_sizes, int n_in,
                              void* d_out, int out_size, void* d_ws, size_t ws_size,
                              hipStream_t stream) {
    const float* x    = (const float*)d_in[0];
    const int*   ei   = (const int*)d_in[1];
    const float* Wl   = (const float*)d_in[2];
    const float* Wr   = (const float*)d_in[3];
    const float* bias = (const float*)d_in[4];
    float* out = (float*)d_out;

    int N = in_sizes[0] / D_FEAT;      // 10000
    int E = in_sizes[1] / 2;           // 160000
    int MT = (N + 127) / 128;          // 79
    int M_PAD = MT * 128;              // 10112

    char* ws = (char*)d_ws;
    size_t off = 0;
    auto take = [&](size_t bytes) -> char* {
        char* p = ws + off;
        off += (bytes + 255) & ~(size_t)255;
        return p;
    };
    ushort_t* xb     = (ushort_t*)take((size_t)M_PAD * D_FEAT * 2);
    ushort_t* mb     = (ushort_t*)take((size_t)M_PAD * D_FEAT * 2);
    ushort_t* BT     = (ushort_t*)take((size_t)D_FEAT * KDIM * 2);
    int*      cnt    = (int*)take((size_t)M_PAD * 4);
    int*      colbuf = (int*)take((size_t)M_PAD * CAP * 4);

    // co-resident grid size (pure host query — capture-safe, deterministic)
    int maxb = 0;
    hipOccupancyMaxActiveBlocksPerMultiprocessor(&maxb, mega_kernel, 256, 0);
    if (maxb < 1) maxb = 1;
    int G = maxb * 256;               // 256 CUs on MI355X
    if (G > 1024) G = 1024;

    void* args[] = {(void*)&Wl, (void*)&Wr, (void*)&x, (void*)&ei, (void*)&bias,
                    (void*)&BT, (void*)&xb, (void*)&mb, (void*)&cnt,
                    (void*)&colbuf, (void*)&out, (void*)&N, (void*)&E,
                    (void*)&M_PAD, (void*)&G};
    hipLaunchCooperativeKernel(mega_kernel, dim3(G), dim3(256), args, 0, stream);
}

// Round 7
// 145.693 us; speedup vs baseline: 2.5048x; 2.5048x over previous
//
#include <hip/hip_runtime.h>
#include <cstdint>
#include <cstddef>

typedef unsigned short ushort_t;
typedef __attribute__((ext_vector_type(8))) short short8;
typedef __attribute__((ext_vector_type(4))) float float4_;

#define GLOBAL_AS __attribute__((address_space(1)))
#define LDS_AS    __attribute__((address_space(3)))

#define D_FEAT 512
#define KDIM   1024
#define CAP    80     // bucket capacity; deg ~ Poisson(16), P(>80) ~ 1e-30

__device__ __forceinline__ ushort_t f2bf(float f) {
    union { float f; unsigned int i; } v; v.f = f;
    unsigned int x = v.i;
    unsigned int r = (x + 0x7fffu + ((x >> 16) & 1u)) >> 16;
    return (ushort_t)r;
}
__device__ __forceinline__ float bfbits_lo(unsigned int u) {
    union { unsigned int i; float f; } v; v.i = u << 16; return v.f;
}
__device__ __forceinline__ float bfbits_hi(unsigned int u) {
    union { unsigned int i; float f; } v; v.i = u & 0xffff0000u; return v.f;
}
__device__ __forceinline__ void acc8(float* acc, uint4 v) {
    acc[0] += bfbits_lo(v.x); acc[1] += bfbits_hi(v.x);
    acc[2] += bfbits_lo(v.y); acc[3] += bfbits_hi(v.y);
    acc[4] += bfbits_lo(v.z); acc[5] += bfbits_hi(v.z);
    acc[6] += bfbits_lo(v.w); acc[7] += bfbits_hi(v.w);
}

// ---------------------------------------------------------------------------
// K1 fused prep, block-partitioned (copy first: it's on agg's critical path):
//   blocks [0,cb)        : copy x fp32 -> dense bf16 xb
//   blocks [cb,cb+40)    : zero cnt
//   blocks [cb+40,cb+168): transpose [W_l;W_r] fp32 -> bf16 BT[n][k]
// ---------------------------------------------------------------------------
__global__ __launch_bounds__(256) void prep_kernel(
    const float* __restrict__ Wl, const float* __restrict__ Wr,
    const float* __restrict__ x, ushort_t* __restrict__ BT,
    ushort_t* __restrict__ xb, int* __restrict__ cnt, int cnt_n,
    int nchunks, int cb) {
    int b = blockIdx.x;
    int t = threadIdx.x;
    if (b < cb) {
        int idx = b * 256 + t;
        if (idx >= nchunks) return;
        int row = idx >> 7;
        int c = (idx & 127) << 2;
        float4 v = *(const float4*)&x[(size_t)row * D_FEAT + c];
        ushort_t o[4] = {f2bf(v.x), f2bf(v.y), f2bf(v.z), f2bf(v.w)};
        *(uint2*)&xb[(size_t)row * D_FEAT + c] = *(const uint2*)o;
    } else if (b < cb + 40) {
        int zi = (b - cb) * 256 + t;
        if (zi < cnt_n) cnt[zi] = 0;
    } else {
        int bb = b - cb - 40;
        __shared__ float tile[64][68];
        int kb = (bb & 15) * 64, nb = (bb >> 4) * 64;
#pragma unroll
        for (int ph = 0; ph < 4; ++ph) {
            int f = t * 4 + ph * 1024;
            int k = f >> 6, n = f & 63;
            int gk = kb + k;
            const float* W = (gk < 512) ? (Wl + (size_t)gk * 512 + nb + n)
                                        : (Wr + (size_t)(gk - 512) * 512 + nb + n);
            *(float4*)&tile[k][n] = *(const float4*)W;
        }
        __syncthreads();
#pragma unroll
        for (int ph = 0; ph < 4; ++ph) {
            int f = t * 4 + ph * 1024;
            int n = f >> 6, k = f & 63;
            ushort_t tmp[4];
#pragma unroll
            for (int j = 0; j < 4; ++j) tmp[j] = f2bf(tile[k + j][n]);
            *(uint2*)&BT[(size_t)(nb + n) * KDIM + kb + k] = *(const uint2*)tmp;
        }
    }
}

// ---------------------------------------------------------------------------
// K2 fused degree-count + bucket scatter: one pass over edges.
// ---------------------------------------------------------------------------
__global__ __launch_bounds__(256) void bucket_kernel(
    const int* __restrict__ ei, int* __restrict__ cnt,
    int* __restrict__ colbuf, int E) {
    int e = blockIdx.x * 256 + threadIdx.x;
    if (e >= E) return;
    int d = ei[E + e];
    int p = atomicAdd(&cnt[d], 1);
    if (p < CAP) colbuf[(size_t)d * CAP + p] = ei[e];
}

// ---------------------------------------------------------------------------
// K3 per-node mean over dense bf16 xb: one wave per node, lane owns 8 feats
// (one uint4/edge).  8-edge unroll (8 gathers in flight) + int4 index loads.
// fp32 accumulate, bf16 mean into dense mb.
// ---------------------------------------------------------------------------
__global__ __launch_bounds__(256) void agg_kernel(
    const ushort_t* __restrict__ xb, ushort_t* __restrict__ mb,
    const int* __restrict__ cnt, const int* __restrict__ colbuf, int n) {
    int w = threadIdx.x >> 6, l = threadIdx.x & 63;
    int node = blockIdx.x * 4 + w;
    if (node >= n) return;
    int f = l << 3;
    const ushort_t* gsrc = xb + f;
    const int* bucket = colbuf + (size_t)node * CAP;
    float acc[8] = {0.f, 0.f, 0.f, 0.f, 0.f, 0.f, 0.f, 0.f};
    int deg = cnt[node];
    int e = deg < CAP ? deg : CAP;
    int j = 0;
    for (; j + 7 < e; j += 8) {
        int4 i0 = *(const int4*)&bucket[j];
        int4 i1 = *(const int4*)&bucket[j + 4];
        uint4 v0 = *(const uint4*)(gsrc + (size_t)i0.x * D_FEAT);
        uint4 v1 = *(const uint4*)(gsrc + (size_t)i0.y * D_FEAT);
        uint4 v2 = *(const uint4*)(gsrc + (size_t)i0.z * D_FEAT);
        uint4 v3 = *(const uint4*)(gsrc + (size_t)i0.w * D_FEAT);
        uint4 v4 = *(const uint4*)(gsrc + (size_t)i1.x * D_FEAT);
        uint4 v5 = *(const uint4*)(gsrc + (size_t)i1.y * D_FEAT);
        uint4 v6 = *(const uint4*)(gsrc + (size_t)i1.z * D_FEAT);
        uint4 v7 = *(const uint4*)(gsrc + (size_t)i1.w * D_FEAT);
        acc8(acc, v0); acc8(acc, v1); acc8(acc, v2); acc8(acc, v3);
        acc8(acc, v4); acc8(acc, v5); acc8(acc, v6); acc8(acc, v7);
    }
    if (j + 3 < e) {
        int4 i0 = *(const int4*)&bucket[j];
        uint4 v0 = *(const uint4*)(gsrc + (size_t)i0.x * D_FEAT);
        uint4 v1 = *(const uint4*)(gsrc + (size_t)i0.y * D_FEAT);
        uint4 v2 = *(const uint4*)(gsrc + (size_t)i0.z * D_FEAT);
        uint4 v3 = *(const uint4*)(gsrc + (size_t)i0.w * D_FEAT);
        acc8(acc, v0); acc8(acc, v1); acc8(acc, v2); acc8(acc, v3);
        j += 4;
    }
    for (; j < e; ++j) {
        uint4 v0 = *(const uint4*)(gsrc + (size_t)bucket[j] * D_FEAT);
        acc8(acc, v0);
    }
    float scale = 1.0f / (float)(deg > 1 ? deg : 1);
    ushort_t o[8];
#pragma unroll
    for (int k = 0; k < 8; ++k) o[k] = f2bf(acc[k] * scale);
    *(uint4*)&mb[(size_t)node * D_FEAT + f] = *(const uint4*)o;
}

// ---------------------------------------------------------------------------
// K4 GEMM: out[m][n] = swish( [mb|xb][m][:] . BT[n][:] + bias[n] ).
// M=M_pad, N=512, K=1024.  128x64 tile, BK=32, 4 waves, 2x4 MFMA/wave.
// ---------------------------------------------------------------------------
__global__ __launch_bounds__(256) void gemm_kernel(
    const ushort_t* __restrict__ mb, const ushort_t* __restrict__ xb,
    const ushort_t* __restrict__ BT, const float* __restrict__ bias,
    float* __restrict__ out, int nrows) {
    __shared__ ushort_t As[128 * 32];  // [m][k], row stride 32
    __shared__ ushort_t Bs[64 * 32];   // [n][k], row stride 32
    int tile_n = blockIdx.x * 64;
    int tile_m = blockIdx.y * 128;
    int tid = threadIdx.x;
    int w = tid >> 6, l = tid & 63;
    int lm = l & 15, q = l >> 4;
    int wm = w * 32;

    float4_ acc[2][4];
#pragma unroll
    for (int i = 0; i < 2; ++i)
#pragma unroll
        for (int j = 0; j < 4; ++j) acc[i][j] = (float4_)(0.f);

    int c0 = w * 64 + l;  // lane-contiguous chunk index per wave

    for (int k0 = 0; k0 < KDIM; k0 += 32) {
        const ushort_t* Asrc = (k0 < 512) ? mb : xb;
        int kk = k0 & 511;
#pragma unroll
        for (int ph = 0; ph < 2; ++ph) {
            int c = c0 + ph * 256;
            int row = c >> 2;
            int koff = (c & 3) << 3;
            const ushort_t* gp = Asrc + (size_t)(tile_m + row) * D_FEAT + kk + koff;
            __builtin_amdgcn_global_load_lds(
                (const GLOBAL_AS unsigned int*)gp,
                (LDS_AS unsigned int*)&As[c * 8], 16, 0, 0);
        }
        {
            int c = c0;
            int row = c >> 2;
            int koff = (c & 3) << 3;
            const ushort_t* gq = BT + (size_t)(tile_n + row) * KDIM + k0 + koff;
            __builtin_amdgcn_global_load_lds(
                (const GLOBAL_AS unsigned int*)gq,
                (LDS_AS unsigned int*)&Bs[c * 8], 16, 0, 0);
        }
        __syncthreads();

        short8 a[2], b[4];
#pragma unroll
        for (int i = 0; i < 2; ++i) {
            int row = wm + i * 16 + lm;
            a[i] = *(const short8*)&As[row * 32 + q * 8];
        }
#pragma unroll
        for (int j = 0; j < 4; ++j) {
            int col = j * 16 + lm;
            b[j] = *(const short8*)&Bs[col * 32 + q * 8];
        }
#pragma unroll
        for (int i = 0; i < 2; ++i)
#pragma unroll
            for (int j = 0; j < 4; ++j)
                acc[i][j] = __builtin_amdgcn_mfma_f32_16x16x32_bf16(
                    a[i], b[j], acc[i][j], 0, 0, 0);
        __syncthreads();
    }

#pragma unroll
    for (int j = 0; j < 4; ++j) {
        int gcol = tile_n + j * 16 + lm;
        float bv = bias[gcol];
#pragma unroll
        for (int i = 0; i < 2; ++i) {
#pragma unroll
            for (int r = 0; r < 4; ++r) {
                int grow = tile_m + wm + i * 16 + q * 4 + r;
                if (grow < nrows) {
                    float h = acc[i][j][r] + bv;
                    float sw = h / (1.f + __expf(-h));
                    out[(size_t)grow * D_FEAT + gcol] = sw;
                }
            }
        }
    }
}

// ---------------------------------------------------------------------------
extern "C" void kernel_launch(void* const* d_in, const int* in_sizes, int n_in,
                              void* d_out, int out_size, void* d_ws, size_t ws_size,
                              hipStream_t stream) {
    const float* x    = (const float*)d_in[0];
    const int*   ei   = (const int*)d_in[1];
    const float* Wl   = (const float*)d_in[2];
    const float* Wr   = (const float*)d_in[3];
    const float* bias = (const float*)d_in[4];
    float* out = (float*)d_out;

    const int N = in_sizes[0] / D_FEAT;      // 10000
    const int E = in_sizes[1] / 2;           // 160000
    const int MT = (N + 127) / 128;          // 79
    const int M_PAD = MT * 128;              // 10112

    char* ws = (char*)d_ws;
    size_t off = 0;
    auto take = [&](size_t bytes) -> char* {
        char* p = ws + off;
        off += (bytes + 255) & ~(size_t)255;
        return p;
    };
    ushort_t* xb     = (ushort_t*)take((size_t)M_PAD * D_FEAT * 2);
    ushort_t* mb     = (ushort_t*)take((size_t)M_PAD * D_FEAT * 2);
    ushort_t* BT     = (ushort_t*)take((size_t)D_FEAT * KDIM * 2);
    int*      cnt    = (int*)take((size_t)M_PAD * 4);
    int*      colbuf = (int*)take((size_t)M_PAD * CAP * 4);

    // 1. fused: x->bf16 copy | zero cnt | weight transpose
    int nchunks = N * (D_FEAT / 4);
    int cb = (nchunks + 255) / 256;
    prep_kernel<<<cb + 40 + 128, 256, 0, stream>>>(
        Wl, Wr, x, BT, xb, cnt, M_PAD, nchunks, cb);

    // 2. fused degree-count + bucket scatter
    int eb = (E + 255) / 256;
    bucket_kernel<<<eb, 256, 0, stream>>>(ei, cnt, colbuf, E);

    // 3. gather-mean (dense bf16 source, contiguous buckets, 8 deep)
    agg_kernel<<<(N + 3) / 4, 256, 0, stream>>>(xb, mb, cnt, colbuf, N);

    // 4. fused GEMM + bias + swish, 128x64 tiles
    gemm_kernel<<<dim3(D_FEAT / 64, MT), 256, 0, stream>>>(mb, xb, BT, bias, out, N);
}